// Round 15
// baseline (294.938 us; speedup 1.0000x reference)
//
#include <hip/hip_runtime.h>
#include <hip/hip_bf16.h>

// SelfAttention (SAGAN-style): B=8, C=256, N=4096, Cp=32, fp32 in/out.
// R15 pipeline:
//   wprep    : Wq|Wk|Wv -> wh/wl bf16 [320][256] + bcat[320] f32
//   xtrans   : x (B,C,N) f32 -> xT (B,N,C) bf16
//   qkv_mfma : MFMA GEMM -> qh/ql (pre-scaled by log2e), kh/kl, vT bf16
//   attn     : fully-MFMA, static softmax, 1 barrier/iter.
// R15 vs R14 (attn): R12-R14 plateaued at ~157us with MfmaUtil 25%, VALU 16%,
//   LDS ~39% -- nothing saturated => lockstep/latency-bound with only 2
//   barrier domains per CU (grid 512, 8-wave blocks). Restructure: 256-thread
//   blocks (4 waves), 64q x 128c, channel-split cs in {0,1}, grid 1024 ->
//   4 independent barrier domains/CU (width 4). QK+exp2 duplicated x2 (+7%
//   total FLOPs); V traffic unchanged (disjoint c-halves). QK acc chains
//   split 3-dep -> 2-dep + VALU add.

constexpr int C  = 256;
constexpr int CP = 32;
constexpr int NPOS = 4096;
constexpr int NB = 8;
constexpr int MT = 64;
constexpr int NT = NPOS / MT;   // 64
constexpr float LOG2E = 1.44269504088896340736f;

typedef __attribute__((ext_vector_type(4))) float  f32x4;
typedef __attribute__((ext_vector_type(4))) short  bf16x4;
typedef __attribute__((ext_vector_type(8))) short  bf16x8;

__device__ __forceinline__ void bar_lds() {
    asm volatile("s_waitcnt lgkmcnt(0)\n\ts_barrier" ::: "memory");
}
__device__ __forceinline__ void wait_vm0() {
    asm volatile("s_waitcnt vmcnt(0)" ::: "memory");
}
__device__ __forceinline__ void wait_vm4() {
    asm volatile("s_waitcnt vmcnt(4)" ::: "memory");
}
__device__ __forceinline__ void wait_vm1() {
    asm volatile("s_waitcnt vmcnt(1)" ::: "memory");
}
__device__ __forceinline__ void gl_lds16(const void* gsrc, void* ldst) {
    typedef const __attribute__((address_space(1))) void* gp_t;
    typedef __attribute__((address_space(3))) void* lp_t;
    __builtin_amdgcn_global_load_lds((gp_t)gsrc, (lp_t)ldst, 16, 0, 0);
}
__device__ __forceinline__ short f2bf(float f) {
    __hip_bfloat16 h = __float2bfloat16(f);
    return __builtin_bit_cast(short, h);
}
__device__ __forceinline__ float ex2(float f) {
    return __builtin_amdgcn_exp2f(f);    // raw v_exp_f32 (2^x)
}
__device__ __forceinline__ f32x4 mfma16(bf16x8 a, bf16x8 b, f32x4 c) {
    return __builtin_amdgcn_mfma_f32_16x16x32_bf16(a, b, c, 0, 0, 0);
}

// ---------------------------------------------------------------------------
// wprep: W -> bf16 hi/lo [320][256] + bcat[320] f32. Grid 320 x 256.
// ---------------------------------------------------------------------------
__global__ __launch_bounds__(256) void wprep_kernel(
    const float* __restrict__ Wq, const float* __restrict__ bq,
    const float* __restrict__ Wk, const float* __restrict__ bk,
    const float* __restrict__ Wv, const float* __restrict__ bv,
    __hip_bfloat16* __restrict__ wh, __hip_bfloat16* __restrict__ wl,
    float* __restrict__ bcat)
{
    const int r = blockIdx.x, c = threadIdx.x;
    float w;
    if (r < 32)      w = Wq[r * 256 + c];
    else if (r < 64) w = Wk[(r - 32) * 256 + c];
    else             w = Wv[(r - 64) * 256 + c];
    __hip_bfloat16 h = __float2bfloat16(w);
    wh[r * 256 + c] = h;
    wl[r * 256 + c] = __float2bfloat16(w - __bfloat162float(h));
    if (c == 0)
        bcat[r] = (r < 32) ? bq[r] : (r < 64) ? bk[r - 32] : bv[r - 64];
}

// ---------------------------------------------------------------------------
// xtrans: x (B,C,N) f32 -> xT (B,N,C) bf16 via [64][65] LDS tiles.
// ---------------------------------------------------------------------------
__global__ __launch_bounds__(256) void xtrans_kernel(
    const float* __restrict__ x, __hip_bfloat16* __restrict__ xT)
{
    __shared__ float xl[64][65];
    const int tid = threadIdx.x;
    const int b   = blockIdx.x >> 8;
    const int rem = blockIdx.x & 255;
    const int c0  = (rem >> 6) << 6;
    const int n0  = (rem & 63) << 6;

    const float* xb = x + ((size_t)b * C + c0) * NPOS + n0;
    #pragma unroll
    for (int k = 0; k < 4; ++k) {
        const int idx = tid + k * 256;
        const int c = idx >> 4, j4 = idx & 15;
        float4 gg = *reinterpret_cast<const float4*>(xb + (size_t)c * NPOS + j4 * 4);
        xl[c][j4 * 4 + 0] = gg.x; xl[c][j4 * 4 + 1] = gg.y;
        xl[c][j4 * 4 + 2] = gg.z; xl[c][j4 * 4 + 3] = gg.w;
    }
    __syncthreads();

    const int nl = tid >> 2, cseg = tid & 3;
    bf16x8 o0, o1;
    #pragma unroll
    for (int j = 0; j < 8; ++j) {
        o0[j] = f2bf(xl[cseg * 16 + j][nl]);
        o1[j] = f2bf(xl[cseg * 16 + 8 + j][nl]);
    }
    __hip_bfloat16* dst = xT + ((size_t)b * NPOS + n0 + nl) * C + c0 + cseg * 16;
    *reinterpret_cast<bf16x8*>(dst)     = o0;
    *reinterpret_cast<bf16x8*>(dst + 8) = o1;
}

// ---------------------------------------------------------------------------
// qkv_mfma: 320 channels x 64 n per block; Q outputs pre-scaled by log2e.
// ---------------------------------------------------------------------------
__global__ __launch_bounds__(512)
__attribute__((amdgpu_waves_per_eu(4)))
void qkv_mfma_kernel(
    const __hip_bfloat16* __restrict__ xT,
    const __hip_bfloat16* __restrict__ wh, const __hip_bfloat16* __restrict__ wl,
    const float* __restrict__ bcat,
    __hip_bfloat16* __restrict__ qh, __hip_bfloat16* __restrict__ ql,
    __hip_bfloat16* __restrict__ kh, __hip_bfloat16* __restrict__ kl,
    __hip_bfloat16* __restrict__ vT)
{
    __shared__ __align__(16) __hip_bfloat16 xlds[16384];    // 32 KB
    __shared__ __align__(16) __hip_bfloat16 wlds[3][4096];  // 24 KB

    const int tid = threadIdx.x;
    const int b  = blockIdx.x & 7;
    const int n0 = (blockIdx.x >> 3) << 6;
    const int l  = tid & 63;
    const int g  = tid >> 6;
    const int G  = l >> 4;
    const int li = l & 15;
    const int cs = g >> 1, ns0 = (g & 1) * 2;

    #pragma unroll
    for (int j = 0; j < 4; ++j)
        gl_lds16(xT + ((size_t)b * NPOS + n0 + l) * C + (j * 8 + g) * 8,
                 xlds + (j * 512 + g * 64) * 8);

    auto stageW = [&](int t, int d) {
        const int ct = t >> 3, ks = t & 7;
        const __hip_bfloat16* src = (g < 4) ? wh : wl;
        const int gg = g & 3;
        gl_lds16(src + (size_t)(ct * 64 + l) * 256 + ks * 32 + gg * 8,
                 &wlds[d][((g >= 4) ? 2048 : 0) + gg * 512]);
    };
    stageW(0, 0);
    stageW(1, 1);

    f32x4 acc0 = (f32x4){0.f, 0.f, 0.f, 0.f};
    f32x4 acc1 = (f32x4){0.f, 0.f, 0.f, 0.f};

    for (int t = 0; t < 40; ++t) {
        wait_vm1();
        bar_lds();
        if (t + 2 < 40) stageW(t + 2, (t + 2) % 3);

        const int ks = t & 7;
        const __hip_bfloat16* wb = wlds[t % 3];
        bf16x8 whf = *reinterpret_cast<const bf16x8*>(wb + (G * 64 + cs * 16 + li) * 8);
        bf16x8 wlf = *reinterpret_cast<const bf16x8*>(wb + 2048 + (G * 64 + cs * 16 + li) * 8);
        bf16x8 xf0 = *reinterpret_cast<const bf16x8*>(
            xlds + (ks * 256 + G * 64 + ns0 * 16 + li) * 8);
        bf16x8 xf1 = *reinterpret_cast<const bf16x8*>(
            xlds + (ks * 256 + G * 64 + (ns0 + 1) * 16 + li) * 8);
        acc0 = mfma16(whf, xf0, acc0);
        acc0 = mfma16(wlf, xf0, acc0);
        acc1 = mfma16(whf, xf1, acc1);
        acc1 = mfma16(wlf, xf1, acc1);

        if (ks == 7) {
            const int ct = t >> 3;
            const int cb = ct * 64 + cs * 16 + G * 4;
            const float4 b4 = *reinterpret_cast<const float4*>(bcat + cb);
            const float bb[4] = {b4.x, b4.y, b4.z, b4.w};
            #pragma unroll
            for (int j = 0; j < 2; ++j) {
                const f32x4 a = j ? acc1 : acc0;
                const int n_abs = n0 + (ns0 + j) * 16 + li;
                if (ct == 0) {
                    __hip_bfloat16* hb = (cs < 2) ? qh : kh;
                    __hip_bfloat16* lb = (cs < 2) ? ql : kl;
                    const float qsc = (cs < 2) ? LOG2E : 1.0f;   // exp2 domain
                    const int cq = (cs < 2) ? cb : cb - 32;
                    const size_t base = ((size_t)b * NPOS + n_abs) * CP + cq;
                    #pragma unroll
                    for (int r = 0; r < 4; ++r) {
                        const float val = (a[r] + bb[r]) * qsc;
                        __hip_bfloat16 h = __float2bfloat16(val);
                        hb[base + r] = h;
                        lb[base + r] = __float2bfloat16(val - __bfloat162float(h));
                    }
                } else {
                    const int cv = cb - 64;
                    #pragma unroll
                    for (int r = 0; r < 4; ++r)
                        vT[((size_t)b * C + cv + r) * NPOS + n_abs] =
                            __float2bfloat16(a[r] + bb[r]);
                }
            }
            acc0 = (f32x4){0.f, 0.f, 0.f, 0.f};
            acc1 = (f32x4){0.f, 0.f, 0.f, 0.f};
        }
    }
}

// ---------------------------------------------------------------------------
// Flash attention, fully-MFMA, static softmax, 1 barrier/iter, MT=64.
//   256 threads (4 waves), block = 64 queries x 128 channels (cs half),
//   grid 1024 -> 4 blocks/CU (4 independent barrier domains).
//   QK: wave w computes S[mi*32..+32][ni2*32..+32] (mi=w>>1, ni2=w&1),
//       hi/lo split-acc (2-dep chain + add). P full tile written per block.
//   PV: wave owns all 64 n x 32 c (c0 = cs*128 + w*32); V in registers.
// ---------------------------------------------------------------------------
__global__ __launch_bounds__(256)
__attribute__((amdgpu_waves_per_eu(4)))
void attn_kernel(
    const __hip_bfloat16* __restrict__ qh, const __hip_bfloat16* __restrict__ ql,
    const __hip_bfloat16* __restrict__ kh, const __hip_bfloat16* __restrict__ kl,
    const __hip_bfloat16* __restrict__ vT, const float* __restrict__ x,
    const float* __restrict__ gamma_p, float* __restrict__ out)
{
    __shared__ __align__(16) __hip_bfloat16 k_lds[2][2][2048]; // 16 KB dbuf
    __shared__ __align__(16) __hip_bfloat16 p_lds[2][64][64];  // 16 KB dbuf
    __shared__ float psm[2][64];

    const int tid = threadIdx.x;
    const int b    = blockIdx.x & 7;     // XCD-aware: one batch per XCD L2
    const int rest = blockIdx.x >> 3;    // 0..127
    const int qt   = rest >> 1;
    const int cs   = rest & 1;           // channel half
    const int l  = tid & 63;
    const int w  = tid >> 6;             // wave 0..3
    const int G  = l >> 4;
    const int li = l & 15;
    const int mi = w >> 1, ni2 = w & 1;
    const int swz = (li & 7) << 4;       // P row byte-swizzle

    const __hip_bfloat16* khb = kh + (size_t)b * NPOS * CP;
    const __hip_bfloat16* klb = kl + (size_t)b * NPOS * CP;
    const __hip_bfloat16* vTb = vT + (size_t)b * C * NPOS;

    // Q fragments for this wave's two n-subtiles
    bf16x8 qhf2[2], qlf2[2];
    #pragma unroll
    for (int nt2 = 0; nt2 < 2; ++nt2) {
        const size_t qoff =
            ((size_t)b * NPOS + qt * 64 + ni2 * 32 + nt2 * 16 + li) * CP + G * 8;
        qhf2[nt2] = *reinterpret_cast<const bf16x8*>(qh + qoff);
        qlf2[nt2] = *reinterpret_cast<const bf16x8*>(ql + qoff);
    }

    // per-thread V fragment base pointers (ct=0,1); c0 = cs*128 + w*32
    const int c0w = cs * 128 + w * 32;
    const __hip_bfloat16* vp0 = vTb + (size_t)(c0w + li) * NPOS + G * 8;
    const __hip_bfloat16* vp1 = vTb + (size_t)(c0w + 16 + li) * NPOS + G * 8;

    f32x4 acc[4][2];
    #pragma unroll
    for (int nt = 0; nt < 4; ++nt)
        #pragma unroll
        for (int ct = 0; ct < 2; ++ct) acc[nt][ct] = (f32x4){0.f, 0.f, 0.f, 0.f};
    float lsum0 = 0.f, lsum1 = 0.f;      // partials for nt2 = 0,1

    // K staging: wave w stages d-group w of kh and kl (2 instrs/wave)
    auto stageK = [&](int tt, int bufd) {
        gl_lds16(khb + (size_t)tt * 2048 + l * 32 + w * 8, &k_lds[bufd][0][w * 512]);
        gl_lds16(klb + (size_t)tt * 2048 + l * 32 + w * 8, &k_lds[bufd][1][w * 512]);
    };
    // QK(tile in k_lds[PB]) + static exp2 -> P into p_lds[PB], lsum partials.
    auto qkp = [&](int PB) {
        bf16x8 khf[2], klf[2];
        #pragma unroll
        for (int mt = 0; mt < 2; ++mt) {
            const int kfo = (G * 64 + (mi * 2 + mt) * 16 + li) * 8;
            khf[mt] = *reinterpret_cast<const bf16x8*>(&k_lds[PB][0][kfo]);
            klf[mt] = *reinterpret_cast<const bf16x8*>(&k_lds[PB][1][kfo]);
        }
        #pragma unroll
        for (int mt = 0; mt < 2; ++mt) {
            #pragma unroll
            for (int nt2 = 0; nt2 < 2; ++nt2) {
                f32x4 u = (f32x4){0.f, 0.f, 0.f, 0.f};
                u = mfma16(khf[mt], qhf2[nt2], u);
                u = mfma16(klf[mt], qhf2[nt2], u);      // 2-dep chain
                f32x4 v = (f32x4){0.f, 0.f, 0.f, 0.f};
                v = mfma16(khf[mt], qlf2[nt2], v);      // independent
                float p[4];
                #pragma unroll
                for (int r = 0; r < 4; ++r) p[r] = ex2(u[r] + v[r]);
                const float psum = (p[0] + p[1]) + (p[2] + p[3]);
                if (nt2 == 0) lsum0 += psum; else lsum1 += psum;
                const int sn = ni2 * 32 + nt2 * 16 + li;
                char* prow = reinterpret_cast<char*>(&p_lds[PB][0][0]) + sn * 128;
                bf16x4 wv = { f2bf(p[0]), f2bf(p[1]), f2bf(p[2]), f2bf(p[3]) };
                *reinterpret_cast<bf16x4*>(
                    prow + ((mi * 64 + mt * 32 + G * 8) ^ swz)) = wv;
            }
        }
    };
    // PV from p_lds[PB] + V register set.
    auto pv = [&](int PB, const bf16x8 vf[4]) {
        const char* pb = reinterpret_cast<const char*>(&p_lds[PB][0][0]);
        #pragma unroll
        for (int s = 0; s < 2; ++s) {
            const bf16x8 af0 = vf[s];        // ct=0 (m half s)
            const bf16x8 af1 = vf[2 + s];    // ct=1
            #pragma unroll
            for (int nt = 0; nt < 4; ++nt) {
                const bf16x8 bfr = *reinterpret_cast<const bf16x8*>(
                    pb + (nt * 16 + li) * 128 + ((s * 64 + G * 16) ^ swz));
                acc[nt][0] = mfma16(af0, bfr, acc[nt][0]);
                acc[nt][1] = mfma16(af1, bfr, acc[nt][1]);
            }
        }
    };
    auto loadV = [&](bf16x8 vf[4], int tt) {
        const __hip_bfloat16* q0 = vp0 + tt * MT;
        const __hip_bfloat16* q1 = vp1 + tt * MT;
        vf[0] = *reinterpret_cast<const bf16x8*>(q0);
        vf[1] = *reinterpret_cast<const bf16x8*>(q0 + 32);
        vf[2] = *reinterpret_cast<const bf16x8*>(q1);
        vf[3] = *reinterpret_cast<const bf16x8*>(q1 + 32);
    };

    bf16x8 vA[4], vB[4];

    // prologue: K(0)->buf0, K(1)->buf1, V(0)->vA; drain; QK(0)->p_lds[0].
    stageK(0, 0);
    stageK(1, 1);
    loadV(vA, 0);
    wait_vm0();
    bar_lds();
    qkp(0);
    bar_lds();                           // publish P(0); K(1) landed

    // main loop, hand-unrolled 2x: 31 pairs cover t = 0..61
    #pragma unroll 1
    for (int tp = 0; tp < 31; ++tp) {
        const int t = tp * 2;
        // ---- instance t (even) ----
        stageK(t + 2, 0);
        __builtin_amdgcn_sched_barrier(0);
        loadV(vB, t + 1);
        __builtin_amdgcn_sched_barrier(0);
        __builtin_amdgcn_s_setprio(1);
        qkp(1);                          // QK(t+1) from k_lds[1] -> p_lds[1]
        pv(0, vA);                       // PV(t) from p_lds[0] + V(t)
        __builtin_amdgcn_s_setprio(0);
        wait_vm4();                      // 2 stageK landed (V x4 in flight)
        bar_lds();
        // ---- instance t+1 (odd) ----
        stageK(t + 3, 1);
        __builtin_amdgcn_sched_barrier(0);
        loadV(vA, t + 2);
        __builtin_amdgcn_sched_barrier(0);
        __builtin_amdgcn_s_setprio(1);
        qkp(0);                          // QK(t+2) from k_lds[0] -> p_lds[0]
        pv(1, vB);                       // PV(t+1)
        __builtin_amdgcn_s_setprio(0);
        wait_vm4();
        bar_lds();
    }
    // ---- t = 62 ----
    stageK(0, 0);                        // wraps (unused)
    __builtin_amdgcn_sched_barrier(0);
    loadV(vB, 63);
    __builtin_amdgcn_sched_barrier(0);
    __builtin_amdgcn_s_setprio(1);
    qkp(1);                              // QK(63) -> p_lds[1]
    pv(0, vA);                           // PV(62)
    __builtin_amdgcn_s_setprio(0);
    wait_vm4();
    bar_lds();
    // ---- t = 63: final PV ----
    pv(1, vB);

    // ---- epilogue: lsum reduce + out = gamma*acc/lsum + x ----
    lsum0 += __shfl_xor(lsum0, 16);
    lsum0 += __shfl_xor(lsum0, 32);
    lsum1 += __shfl_xor(lsum1, 16);
    lsum1 += __shfl_xor(lsum1, 32);
    if (G == 0) {
        psm[mi][ni2 * 32 + li]      = lsum0;
        psm[mi][ni2 * 32 + 16 + li] = lsum1;
    }
    bar_lds();

    const float gamma = *gamma_p;
    const float* xb = x   + (size_t)b * C * NPOS;
    float*       ob = out + (size_t)b * C * NPOS;

    #pragma unroll
    for (int nt = 0; nt < 4; ++nt) {
        const int cidx = nt * 16 + li;
        const float inv = 1.0f / (psm[0][cidx] + psm[1][cidx]);
        const int n = qt * 64 + cidx;
        #pragma unroll
        for (int ct = 0; ct < 2; ++ct) {
            const int c0 = c0w + ct * 16 + G * 4;
            #pragma unroll
            for (int r = 0; r < 4; ++r) {
                const size_t idx = (size_t)(c0 + r) * NPOS + n;
                ob[idx] = gamma * acc[nt][ct][r] * inv + xb[idx];
            }
        }
    }
}

extern "C" void kernel_launch(void* const* d_in, const int* in_sizes, int n_in,
                              void* d_out, int out_size, void* d_ws, size_t ws_size,
                              hipStream_t stream) {
    const float* x  = (const float*)d_in[0];
    const float* Wq = (const float*)d_in[1];
    const float* bq = (const float*)d_in[2];
    const float* Wk = (const float*)d_in[3];
    const float* bk = (const float*)d_in[4];
    const float* Wv = (const float*)d_in[5];
    const float* bv = (const float*)d_in[6];
    const float* gamma = (const float*)d_in[7];
    float* out = (float*)d_out;

    const size_t qk_n = (size_t)NB * NPOS * CP;          // 1M elements
    const size_t v_n  = (size_t)NB * C * NPOS;           // 8.4M elements
    __hip_bfloat16* qhb = (__hip_bfloat16*)d_ws;
    __hip_bfloat16* qlb = qhb + qk_n;
    __hip_bfloat16* khb = qlb + qk_n;
    __hip_bfloat16* klb = khb + qk_n;
    __hip_bfloat16* vT  = klb + qk_n;
    __hip_bfloat16* xT  = vT + v_n;
    __hip_bfloat16* wh  = xT + v_n;
    __hip_bfloat16* wl  = wh + 320 * 256;
    float*          bcat = (float*)(wl + 320 * 256);

    xtrans_kernel<<<NB * 4 * 64, 256, 0, stream>>>(x, xT);
    wprep_kernel<<<320, 256, 0, stream>>>(Wq, bq, Wk, bk, Wv, bv, wh, wl, bcat);
    qkv_mfma_kernel<<<NB * (NPOS / 64), 512, 0, stream>>>(xT, wh, wl, bcat,
                                                          qhb, qlb, khb, klb, vT);
    // grid: ((qt*2 + cs)*8 + b) -> blockIdx&7 = batch = XCD; 1024 blocks
    attn_kernel<<<NB * (NPOS / 64) * 2, 256, 0, stream>>>(qhb, qlb, khb, klb, vT,
                                                          x, gamma, out);
}